// Round 1
// baseline (312.039 us; speedup 1.0000x reference)
//
#include <hip/hip_runtime.h>
#include <math.h>

#define TOTAL   8192
#define GENES   5000
#define NDS     64          // points per cloud
#define NB      128         // TOTAL / NDS
#define NSHARED 128
#define DC      64          // D-chunk staged in LDS

// ws layout (floats): [0]=gene acc, [1]=cell acc, grams start at GRAM_OFF
#define GRAM_OFF 64

__global__ __launch_bounds__(64) void k_zero(float* ws) {
    ws[threadIdx.x] = 0.0f;
}

// ---------------------------------------------------------------------------
// K1: partial Gram matrices per (batch, D-slice).
// grams[(b*splitD + c)][m][64*64], m: 0=xy, 1=xx, 2=yy
// ---------------------------------------------------------------------------
__global__ __launch_bounds__(256) void k_gene_gram(const float* __restrict__ X,
                                                   const float* __restrict__ Y,
                                                   float* __restrict__ grams,
                                                   int splitD, int Dper) {
    const int blk = blockIdx.x;
    const int b = blk / splitD, c = blk % splitD;
    const int d0 = c * Dper;
    const int d1 = min(GENES, d0 + Dper);

    const float* __restrict__ xb = X + (size_t)b * NDS * GENES;
    const float* __restrict__ yb = Y + (size_t)b * NDS * GENES;

    // [d][i] layout, 16B blocks XOR-swizzled by ((d>>2)&7)
    __shared__ __align__(16) float sx[DC * 64];
    __shared__ __align__(16) float sy[DC * 64];

    const int t  = threadIdx.x;
    const int ti = t & 15, tj = t >> 4;   // 16x16 thread grid, 4x4 tile each
    const int i0 = ti << 2, j0 = tj << 2;

    float axy[4][4] = {{0}}, axx[4][4] = {{0}}, ayy[4][4] = {{0}};

    for (int dd0 = d0; dd0 < d1; dd0 += DC) {
        __syncthreads();   // previous chunk fully consumed
        // ---- stage chunk: coalesced float4 loads, transposed+swizzled LDS ----
#pragma unroll
        for (int k = 0; k < 4; ++k) {
            const int idx = t + 256 * k;      // 0..1023
            const int i   = idx >> 4;         // row 0..63
            const int c4  = idx & 15;         // float4 column
            const int d   = dd0 + (c4 << 2);
            float vx[4] = {0.f, 0.f, 0.f, 0.f};
            float vy[4] = {0.f, 0.f, 0.f, 0.f};
            if (d + 3 < d1) {
                const float4 fx = *(const float4*)(xb + (size_t)i * GENES + d);
                const float4 fy = *(const float4*)(yb + (size_t)i * GENES + d);
                vx[0]=fx.x; vx[1]=fx.y; vx[2]=fx.z; vx[3]=fx.w;
                vy[0]=fy.x; vy[1]=fy.y; vy[2]=fy.z; vy[3]=fy.w;
            } else if (d < d1) {
                for (int q = 0; q < d1 - d; ++q) {
                    vx[q] = xb[(size_t)i * GENES + d + q];
                    vy[q] = yb[(size_t)i * GENES + d + q];
                }
            }
            const int Bq = i >> 2, ir = i & 3;
#pragma unroll
            for (int q = 0; q < 4; ++q) {
                const int dl  = (c4 << 2) + q;
                const int off = dl * 64 + ((Bq ^ ((dl >> 2) & 7)) << 2) + ir;
                sx[off] = vx[q];
                sy[off] = vy[q];
            }
        }
        __syncthreads();
        // ---- compute: 48 FMA per d per thread ----
#pragma unroll 4
        for (int d = 0; d < DC; ++d) {
            const int s = (d >> 2) & 7;
            const float* bx = sx + d * 64;
            const float* by = sy + d * 64;
            const float4 xi4 = *(const float4*)(bx + ((ti ^ s) << 2));
            const float4 xj4 = *(const float4*)(bx + ((tj ^ s) << 2));
            const float4 yi4 = *(const float4*)(by + ((ti ^ s) << 2));
            const float4 yj4 = *(const float4*)(by + ((tj ^ s) << 2));
            const float* xi = &xi4.x;
            const float* xj = &xj4.x;
            const float* yi = &yi4.x;
            const float* yj = &yj4.x;
#pragma unroll
            for (int ii = 0; ii < 4; ++ii) {
#pragma unroll
                for (int jj = 0; jj < 4; ++jj) {
                    axy[ii][jj] = fmaf(xi[ii], yj[jj], axy[ii][jj]);
                    axx[ii][jj] = fmaf(xi[ii], xj[jj], axx[ii][jj]);
                    ayy[ii][jj] = fmaf(yi[ii], yj[jj], ayy[ii][jj]);
                }
            }
        }
    }

    float* g = grams + (size_t)(b * splitD + c) * 3 * 4096;
#pragma unroll
    for (int ii = 0; ii < 4; ++ii) {
        float4 v;
        v.x = axy[ii][0]; v.y = axy[ii][1]; v.z = axy[ii][2]; v.w = axy[ii][3];
        *(float4*)(g + 0 * 4096 + (i0 + ii) * 64 + j0) = v;
        v.x = axx[ii][0]; v.y = axx[ii][1]; v.z = axx[ii][2]; v.w = axx[ii][3];
        *(float4*)(g + 1 * 4096 + (i0 + ii) * 64 + j0) = v;
        v.x = ayy[ii][0]; v.y = ayy[ii][1]; v.z = ayy[ii][2]; v.w = ayy[ii][3];
        *(float4*)(g + 2 * 4096 + (i0 + ii) * 64 + j0) = v;
    }
}

// ---------------------------------------------------------------------------
// K2: per batch — reduce Gram partials, distances, mean, accumulate.
// ---------------------------------------------------------------------------
__global__ __launch_bounds__(256) void k_gene_dist(const float* __restrict__ grams,
                                                   float* __restrict__ acc,
                                                   int splitD) {
    const int b = blockIdx.x, t = threadIdx.x;
    __shared__ __align__(16) float G[3 * 4096];   // 48 KB
    __shared__ float red[4];

    for (int m = 0; m < 3; ++m) {
#pragma unroll
        for (int k = 0; k < 16; ++k) {
            const int e = t + 256 * k;
            float s = 0.f;
            for (int c = 0; c < splitD; ++c)
                s += grams[((size_t)(b * splitD + c) * 3 + m) * 4096 + e];
            G[m * 4096 + e] = s;
        }
    }
    __syncthreads();

    float local = 0.f;
#pragma unroll
    for (int k = 0; k < 16; ++k) {
        const int e = t + 256 * k;
        const int i = e >> 6, j = e & 63;
        const float gxy = G[e];
        const float gxx = G[4096 + e];
        const float gyy = G[8192 + e];
        const float nxi = G[4096 + i * 65], nxj = G[4096 + j * 65];
        const float nyi = G[8192 + i * 65], nyj = G[8192 + j * 65];
        const float dxy = sqrtf(fmaxf(nxi + nyj - 2.f * gxy, 0.f));
        const float dxx = sqrtf(fmaxf(nxi + nxj - 2.f * gxx, 0.f));
        const float dyy = sqrtf(fmaxf(nyi + nyj - 2.f * gyy, 0.f));
        local += dxy - 0.5f * (dxx + dyy);
    }
#pragma unroll
    for (int off = 32; off; off >>= 1) local += __shfl_down(local, off);
    if ((t & 63) == 0) red[t >> 6] = local;
    __syncthreads();
    if (t == 0) {
        const float bl = red[0] + red[1] + red[2] + red[3];
        atomicAdd(acc, bl * (1.0f / (4096.0f * (float)NB)));
    }
}

// ---------------------------------------------------------------------------
// K3: cell-level — one block per shared gene s. Clouds: 64 points x 128 dims.
// ---------------------------------------------------------------------------
__global__ __launch_bounds__(256) void k_cell(const float* __restrict__ X,
                                              const float* __restrict__ Y,
                                              float* __restrict__ acc) {
    const int s   = blockIdx.x;
    const int col = GENES - NSHARED + s;
    const int t   = threadIdx.x;

    // cx tile [b][n] at [0..8191], cy at [8192..16383]; reused for Grams after
    __shared__ __align__(16) float lds[16384];    // 64 KB

#pragma unroll
    for (int k = 0; k < 32; ++k) {
        const int idx = t + 256 * k;              // = b*64 + n, 0..8191
        lds[idx]        = X[(size_t)idx * GENES + col];
        lds[8192 + idx] = Y[(size_t)idx * GENES + col];
    }
    __syncthreads();

    const int ti = t & 15, tj = t >> 4;
    const int i0 = ti << 2, j0 = tj << 2;
    float axy[4][4] = {{0}}, axx[4][4] = {{0}}, ayy[4][4] = {{0}};

#pragma unroll 4
    for (int bb = 0; bb < NB; ++bb) {
        const float4 xi4 = *(const float4*)(lds + bb * 64 + i0);
        const float4 xj4 = *(const float4*)(lds + bb * 64 + j0);
        const float4 yi4 = *(const float4*)(lds + 8192 + bb * 64 + i0);
        const float4 yj4 = *(const float4*)(lds + 8192 + bb * 64 + j0);
        const float* xi = &xi4.x;
        const float* xj = &xj4.x;
        const float* yi = &yi4.x;
        const float* yj = &yj4.x;
#pragma unroll
        for (int ii = 0; ii < 4; ++ii) {
#pragma unroll
            for (int jj = 0; jj < 4; ++jj) {
                axy[ii][jj] = fmaf(xi[ii], yj[jj], axy[ii][jj]);
                axx[ii][jj] = fmaf(xi[ii], xj[jj], axx[ii][jj]);
                ayy[ii][jj] = fmaf(yi[ii], yj[jj], ayy[ii][jj]);
            }
        }
    }
    __syncthreads();
    // write Grams into lds[0..12287] (tiles no longer needed)
#pragma unroll
    for (int ii = 0; ii < 4; ++ii) {
        float4 v;
        v.x = axy[ii][0]; v.y = axy[ii][1]; v.z = axy[ii][2]; v.w = axy[ii][3];
        *(float4*)(lds + 0 * 4096 + (i0 + ii) * 64 + j0) = v;
        v.x = axx[ii][0]; v.y = axx[ii][1]; v.z = axx[ii][2]; v.w = axx[ii][3];
        *(float4*)(lds + 1 * 4096 + (i0 + ii) * 64 + j0) = v;
        v.x = ayy[ii][0]; v.y = ayy[ii][1]; v.z = ayy[ii][2]; v.w = ayy[ii][3];
        *(float4*)(lds + 2 * 4096 + (i0 + ii) * 64 + j0) = v;
    }
    __syncthreads();

    float local = 0.f;
#pragma unroll
    for (int k = 0; k < 16; ++k) {
        const int e = t + 256 * k;
        const int i = e >> 6, j = e & 63;
        const float gxy = lds[e];
        const float gxx = lds[4096 + e];
        const float gyy = lds[8192 + e];
        const float nxi = lds[4096 + i * 65], nxj = lds[4096 + j * 65];
        const float nyi = lds[8192 + i * 65], nyj = lds[8192 + j * 65];
        const float dxy = sqrtf(fmaxf(nxi + nyj - 2.f * gxy, 0.f));
        const float dxx = sqrtf(fmaxf(nxi + nxj - 2.f * gxx, 0.f));
        const float dyy = sqrtf(fmaxf(nyi + nyj - 2.f * gyy, 0.f));
        local += dxy - 0.5f * (dxx + dyy);
    }
#pragma unroll
    for (int off = 32; off; off >>= 1) local += __shfl_down(local, off);
    __syncthreads();                 // done reading lds as Grams
    if ((t & 63) == 0) lds[t >> 6] = local;
    __syncthreads();
    if (t == 0) {
        const float bl = lds[0] + lds[1] + lds[2] + lds[3];
        atomicAdd(acc, bl * (1.0f / (4096.0f * (float)NSHARED)));
    }
}

__global__ void k_final(const float* __restrict__ acc, float* __restrict__ out) {
    out[0] = acc[0] + acc[1];
}

extern "C" void kernel_launch(void* const* d_in, const int* in_sizes, int n_in,
                              void* d_out, int out_size, void* d_ws, size_t ws_size,
                              hipStream_t stream) {
    const float* X = (const float*)d_in[0];
    const float* Y = (const float*)d_in[1];
    float* out = (float*)d_out;
    float* ws  = (float*)d_ws;

    // pick splitD (D-slices per batch) so partial-Gram buffer fits in ws
    int splitD = 4;
    while (splitD > 1 &&
           ((size_t)GRAM_OFF + (size_t)splitD * NB * 3 * 4096) * sizeof(float) > ws_size)
        splitD >>= 1;
    const int chunks = (GENES + DC - 1) / DC;            // 79
    const int cper   = (chunks + splitD - 1) / splitD;   // chunks per slice
    const int Dper   = cper * DC;                        // multiple of DC (alignment!)

    float* acc   = ws;
    float* grams = ws + GRAM_OFF;

    hipLaunchKernelGGL(k_zero,      dim3(1),            dim3(64),  0, stream, acc);
    hipLaunchKernelGGL(k_gene_gram, dim3(NB * splitD),  dim3(256), 0, stream,
                       X, Y, grams, splitD, Dper);
    hipLaunchKernelGGL(k_gene_dist, dim3(NB),           dim3(256), 0, stream,
                       grams, acc + 0, splitD);
    hipLaunchKernelGGL(k_cell,      dim3(NSHARED),      dim3(256), 0, stream,
                       X, Y, acc + 1);
    hipLaunchKernelGGL(k_final,     dim3(1),            dim3(1),   0, stream, acc, out);
}

// Round 2
// 192.046 us; speedup vs baseline: 1.6248x; 1.6248x over previous
//
#include <hip/hip_runtime.h>
#include <math.h>

#define TOTAL   8192
#define GENES   5000
#define NDS     64          // points per cloud
#define NB      128         // TOTAL / NDS
#define NSHARED 128
#define KC      64          // K-chunk staged in LDS

// ws layout (floats): [0]=gene acc, [1]=cell acc, grams start at GRAM_OFF
#define GRAM_OFF 64

typedef __attribute__((ext_vector_type(8)))  short          short8;
typedef __attribute__((ext_vector_type(4)))  unsigned short ushort4v;
typedef __attribute__((ext_vector_type(16))) float          f32x16;

static __device__ inline unsigned short f2bf(float f) {
    unsigned int u = __builtin_bit_cast(unsigned int, f);
    unsigned int r = (u + 0x7fffu + ((u >> 16) & 1u)) >> 16;   // RNE
    return (unsigned short)r;
}
static __device__ inline float bf2f(unsigned short h) {
    unsigned int u = ((unsigned int)h) << 16;
    return __builtin_bit_cast(float, u);
}

__global__ __launch_bounds__(64) void k_zero(float* ws) {
    ws[threadIdx.x] = 0.0f;
}

// ---------------------------------------------------------------------------
// K1: partial Gram matrices per (batch, K-slice) via bf16 hi/lo split MFMA.
// Gxy = XhYh + XhYl + XlYh  (lo*lo dropped, ~3e-4 abs on O(1e4) entries)
// grams[(b*splitD + c)][m][64*64], m: 0=xy, 1=xx, 2=yy
// ---------------------------------------------------------------------------
__global__ __launch_bounds__(256) void k_gene_gram_mfma(const float* __restrict__ X,
                                                        const float* __restrict__ Y,
                                                        float* __restrict__ grams,
                                                        int splitD, int Dper) {
    const int blk = blockIdx.x;
    const int b = blk / splitD, c = blk % splitD;
    const int d0 = c * Dper;
    const int d1 = min(GENES, d0 + Dper);

    const float* __restrict__ xb = X + (size_t)b * NDS * GENES;
    const float* __restrict__ yb = Y + (size_t)b * NDS * GENES;

    // [m][k] bf16 tiles, element-XOR swizzle  k ^ ((m&7)<<3)  (16B granularity)
    __shared__ __align__(16) unsigned short sXh[NDS * KC], sXl[NDS * KC];
    __shared__ __align__(16) unsigned short sYh[NDS * KC], sYl[NDS * KC];

    const int t    = threadIdx.x;
    const int lane = t & 63;
    const int w    = t >> 6;           // wave 0..3
    const int qr   = w >> 1, qc = w & 1;   // 32x32 output quadrant
    const int lm   = lane & 31;
    const int kh   = (lane >> 5) << 3;     // k-half offset 0/8 (assumed; cancels)

    const int mr = (qr << 5) + lm;     // A-side row
    const int mc = (qc << 5) + lm;     // B-side row (Gram col)

    f32x16 axy = {0,0,0,0,0,0,0,0,0,0,0,0,0,0,0,0};
    f32x16 axx = {0,0,0,0,0,0,0,0,0,0,0,0,0,0,0,0};
    f32x16 ayy = {0,0,0,0,0,0,0,0,0,0,0,0,0,0,0,0};

    for (int dd0 = d0; dd0 < d1; dd0 += KC) {
        __syncthreads();   // previous chunk fully consumed
        // ---- stage: coalesced float4 loads -> hi/lo bf16, swizzled LDS ----
#pragma unroll
        for (int it = 0; it < 4; ++it) {
            const int c4 = t & 15;                 // float4 column
            const int m  = (t >> 4) + (it << 4);   // row 0..63
            const int d  = dd0 + (c4 << 2);
            float vx[4] = {0.f, 0.f, 0.f, 0.f};
            float vy[4] = {0.f, 0.f, 0.f, 0.f};
            if (d + 3 < d1) {
                const float4 fx = *(const float4*)(xb + (size_t)m * GENES + d);
                const float4 fy = *(const float4*)(yb + (size_t)m * GENES + d);
                vx[0]=fx.x; vx[1]=fx.y; vx[2]=fx.z; vx[3]=fx.w;
                vy[0]=fy.x; vy[1]=fy.y; vy[2]=fy.z; vy[3]=fy.w;
            } else if (d < d1) {
                for (int q = 0; q < d1 - d; ++q) {
                    vx[q] = xb[(size_t)m * GENES + d + q];
                    vy[q] = yb[(size_t)m * GENES + d + q];
                }
            }
            ushort4v xh, xl, yh, yl;
#pragma unroll
            for (int q = 0; q < 4; ++q) {
                const unsigned short h = f2bf(vx[q]);
                xh[q] = h; xl[q] = f2bf(vx[q] - bf2f(h));
                const unsigned short g = f2bf(vy[q]);
                yh[q] = g; yl[q] = f2bf(vy[q] - bf2f(g));
            }
            const int e = m * KC + (((c4 << 2)) ^ ((m & 7) << 3));
            *(ushort4v*)&sXh[e] = xh;
            *(ushort4v*)&sXl[e] = xl;
            *(ushort4v*)&sYh[e] = yh;
            *(ushort4v*)&sYl[e] = yl;
        }
        __syncthreads();
        // ---- compute: 4 K=16 steps, 9 MFMAs each into 3 accumulators ----
#pragma unroll
        for (int ks = 0; ks < 4; ++ks) {
            const int kb = (ks << 4) + kh;
            const int er = mr * KC + (kb ^ ((mr & 7) << 3));
            const int ec = mc * KC + (kb ^ ((mc & 7) << 3));
            const short8 xhr = *(const short8*)&sXh[er];
            const short8 xlr = *(const short8*)&sXl[er];
            const short8 yhr = *(const short8*)&sYh[er];
            const short8 ylr = *(const short8*)&sYl[er];
            const short8 xhc = *(const short8*)&sXh[ec];
            const short8 xlc = *(const short8*)&sXl[ec];
            const short8 yhc = *(const short8*)&sYh[ec];
            const short8 ylc = *(const short8*)&sYl[ec];
            axy = __builtin_amdgcn_mfma_f32_32x32x16_bf16(xhr, yhc, axy, 0, 0, 0);
            axx = __builtin_amdgcn_mfma_f32_32x32x16_bf16(xhr, xhc, axx, 0, 0, 0);
            ayy = __builtin_amdgcn_mfma_f32_32x32x16_bf16(yhr, yhc, ayy, 0, 0, 0);
            axy = __builtin_amdgcn_mfma_f32_32x32x16_bf16(xhr, ylc, axy, 0, 0, 0);
            axx = __builtin_amdgcn_mfma_f32_32x32x16_bf16(xhr, xlc, axx, 0, 0, 0);
            ayy = __builtin_amdgcn_mfma_f32_32x32x16_bf16(yhr, ylc, ayy, 0, 0, 0);
            axy = __builtin_amdgcn_mfma_f32_32x32x16_bf16(xlr, yhc, axy, 0, 0, 0);
            axx = __builtin_amdgcn_mfma_f32_32x32x16_bf16(xlr, xhc, axx, 0, 0, 0);
            ayy = __builtin_amdgcn_mfma_f32_32x32x16_bf16(ylr, yhc, ayy, 0, 0, 0);
        }
    }

    // ---- writeout: verified 32x32 C/D layout: col=lane&31,
    //      row=(reg&3)+8*(reg>>2)+4*(lane>>5) ----
    float* g = grams + (size_t)(b * splitD + c) * 3 * 4096;
    const int col = (qc << 5) + lm;
#pragma unroll
    for (int r = 0; r < 16; ++r) {
        const int row = (qr << 5) + (r & 3) + ((r >> 2) << 3) + ((lane >> 5) << 2);
        g[0 * 4096 + row * 64 + col] = axy[r];
        g[1 * 4096 + row * 64 + col] = axx[r];
        g[2 * 4096 + row * 64 + col] = ayy[r];
    }
}

// ---------------------------------------------------------------------------
// K2: per batch — reduce Gram partials, distances, mean, accumulate.
// ---------------------------------------------------------------------------
__global__ __launch_bounds__(256) void k_gene_dist(const float* __restrict__ grams,
                                                   float* __restrict__ acc,
                                                   int splitD) {
    const int b = blockIdx.x, t = threadIdx.x;
    __shared__ __align__(16) float G[3 * 4096];   // 48 KB
    __shared__ float red[4];

    for (int m = 0; m < 3; ++m) {
#pragma unroll
        for (int k = 0; k < 16; ++k) {
            const int e = t + 256 * k;
            float s = 0.f;
            for (int c = 0; c < splitD; ++c)
                s += grams[((size_t)(b * splitD + c) * 3 + m) * 4096 + e];
            G[m * 4096 + e] = s;
        }
    }
    __syncthreads();

    float local = 0.f;
#pragma unroll
    for (int k = 0; k < 16; ++k) {
        const int e = t + 256 * k;
        const int i = e >> 6, j = e & 63;
        const float gxy = G[e];
        const float gxx = G[4096 + e];
        const float gyy = G[8192 + e];
        const float nxi = G[4096 + i * 65], nxj = G[4096 + j * 65];
        const float nyi = G[8192 + i * 65], nyj = G[8192 + j * 65];
        const float dxy = sqrtf(fmaxf(nxi + nyj - 2.f * gxy, 0.f));
        const float dxx = sqrtf(fmaxf(nxi + nxj - 2.f * gxx, 0.f));
        const float dyy = sqrtf(fmaxf(nyi + nyj - 2.f * gyy, 0.f));
        local += dxy - 0.5f * (dxx + dyy);
    }
#pragma unroll
    for (int off = 32; off; off >>= 1) local += __shfl_down(local, off);
    if ((t & 63) == 0) red[t >> 6] = local;
    __syncthreads();
    if (t == 0) {
        const float bl = red[0] + red[1] + red[2] + red[3];
        atomicAdd(acc, bl * (1.0f / (4096.0f * (float)NB)));
    }
}

// ---------------------------------------------------------------------------
// K3: cell-level — one block per shared gene s. Clouds: 64 points x 128 dims.
// ---------------------------------------------------------------------------
__global__ __launch_bounds__(256) void k_cell(const float* __restrict__ X,
                                              const float* __restrict__ Y,
                                              float* __restrict__ acc) {
    const int s   = blockIdx.x;
    const int col = GENES - NSHARED + s;
    const int t   = threadIdx.x;

    // cx tile [b][n] at [0..8191], cy at [8192..16383]; reused for Grams after
    __shared__ __align__(16) float lds[16384];    // 64 KB

#pragma unroll
    for (int k = 0; k < 32; ++k) {
        const int idx = t + 256 * k;              // = b*64 + n, 0..8191
        lds[idx]        = X[(size_t)idx * GENES + col];
        lds[8192 + idx] = Y[(size_t)idx * GENES + col];
    }
    __syncthreads();

    const int ti = t & 15, tj = t >> 4;
    const int i0 = ti << 2, j0 = tj << 2;
    float axy[4][4] = {{0}}, axx[4][4] = {{0}}, ayy[4][4] = {{0}};

#pragma unroll 4
    for (int bb = 0; bb < NB; ++bb) {
        const float4 xi4 = *(const float4*)(lds + bb * 64 + i0);
        const float4 xj4 = *(const float4*)(lds + bb * 64 + j0);
        const float4 yi4 = *(const float4*)(lds + 8192 + bb * 64 + i0);
        const float4 yj4 = *(const float4*)(lds + 8192 + bb * 64 + j0);
        const float* xi = &xi4.x;
        const float* xj = &xj4.x;
        const float* yi = &yi4.x;
        const float* yj = &yj4.x;
#pragma unroll
        for (int ii = 0; ii < 4; ++ii) {
#pragma unroll
            for (int jj = 0; jj < 4; ++jj) {
                axy[ii][jj] = fmaf(xi[ii], yj[jj], axy[ii][jj]);
                axx[ii][jj] = fmaf(xi[ii], xj[jj], axx[ii][jj]);
                ayy[ii][jj] = fmaf(yi[ii], yj[jj], ayy[ii][jj]);
            }
        }
    }
    __syncthreads();
    // write Grams into lds[0..12287] (tiles no longer needed)
#pragma unroll
    for (int ii = 0; ii < 4; ++ii) {
        float4 v;
        v.x = axy[ii][0]; v.y = axy[ii][1]; v.z = axy[ii][2]; v.w = axy[ii][3];
        *(float4*)(lds + 0 * 4096 + (i0 + ii) * 64 + j0) = v;
        v.x = axx[ii][0]; v.y = axx[ii][1]; v.z = axx[ii][2]; v.w = axx[ii][3];
        *(float4*)(lds + 1 * 4096 + (i0 + ii) * 64 + j0) = v;
        v.x = ayy[ii][0]; v.y = ayy[ii][1]; v.z = ayy[ii][2]; v.w = ayy[ii][3];
        *(float4*)(lds + 2 * 4096 + (i0 + ii) * 64 + j0) = v;
    }
    __syncthreads();

    float local = 0.f;
#pragma unroll
    for (int k = 0; k < 16; ++k) {
        const int e = t + 256 * k;
        const int i = e >> 6, j = e & 63;
        const float gxy = lds[e];
        const float gxx = lds[4096 + e];
        const float gyy = lds[8192 + e];
        const float nxi = lds[4096 + i * 65], nxj = lds[4096 + j * 65];
        const float nyi = lds[8192 + i * 65], nyj = lds[8192 + j * 65];
        const float dxy = sqrtf(fmaxf(nxi + nyj - 2.f * gxy, 0.f));
        const float dxx = sqrtf(fmaxf(nxi + nxj - 2.f * gxx, 0.f));
        const float dyy = sqrtf(fmaxf(nyi + nyj - 2.f * gyy, 0.f));
        local += dxy - 0.5f * (dxx + dyy);
    }
#pragma unroll
    for (int off = 32; off; off >>= 1) local += __shfl_down(local, off);
    __syncthreads();                 // done reading lds as Grams
    if ((t & 63) == 0) lds[t >> 6] = local;
    __syncthreads();
    if (t == 0) {
        const float bl = lds[0] + lds[1] + lds[2] + lds[3];
        atomicAdd(acc, bl * (1.0f / (4096.0f * (float)NSHARED)));
    }
}

__global__ void k_final(const float* __restrict__ acc, float* __restrict__ out) {
    out[0] = acc[0] + acc[1];
}

extern "C" void kernel_launch(void* const* d_in, const int* in_sizes, int n_in,
                              void* d_out, int out_size, void* d_ws, size_t ws_size,
                              hipStream_t stream) {
    const float* X = (const float*)d_in[0];
    const float* Y = (const float*)d_in[1];
    float* out = (float*)d_out;
    float* ws  = (float*)d_ws;

    // pick splitD (K-slices per batch) so partial-Gram buffer fits in ws
    int splitD = 4;
    while (splitD > 1 &&
           ((size_t)GRAM_OFF + (size_t)splitD * NB * 3 * 4096) * sizeof(float) > ws_size)
        splitD >>= 1;
    const int chunks = (GENES + KC - 1) / KC;            // 79
    const int cper   = (chunks + splitD - 1) / splitD;   // chunks per slice
    const int Dper   = cper * KC;                        // multiple of KC

    float* acc   = ws;
    float* grams = ws + GRAM_OFF;

    hipLaunchKernelGGL(k_zero,           dim3(1),           dim3(64),  0, stream, acc);
    hipLaunchKernelGGL(k_gene_gram_mfma, dim3(NB * splitD), dim3(256), 0, stream,
                       X, Y, grams, splitD, Dper);
    hipLaunchKernelGGL(k_gene_dist,      dim3(NB),          dim3(256), 0, stream,
                       grams, acc + 0, splitD);
    hipLaunchKernelGGL(k_cell,           dim3(NSHARED),     dim3(256), 0, stream,
                       X, Y, acc + 1);
    hipLaunchKernelGGL(k_final,          dim3(1),           dim3(1),   0, stream, acc, out);
}